// Round 1
// 1874.535 us; speedup vs baseline: 1.1125x; 1.1125x over previous
//
#include <hip/hip_runtime.h>
#include <math.h>

#define NN    6144
#define MP1   6145
#define R     4                  // rows per lane per step
#define KC    4                  // columns per lane
#define WCH   (KC * 64)          // 256 columns per wave
#define GCH   (NN / WCH)         // 24 waves / workgroups
#define RTS   16                 // steps per handoff tile (= 64 rows / flag)
#define NWS   (NN / R)           // 1536 working steps per wave
#define STEPS (NWS + 63)         // + lane-stagger fill = 1599
#define FINF  99999.0f

typedef float f4a __attribute__((ext_vector_type(4), aligned(4)));   // unaligned-ok store
typedef float f4v __attribute__((ext_vector_type(4), aligned(16)));  // aligned vec

__device__ __forceinline__ float readlane_f(float v, int l) {
    return __int_as_float(__builtin_amdgcn_readlane(__float_as_int(v), l));
}
// lane i <- lane i-1, via DPP wave_shr:1 (VALU-speed, replaces ds_bpermute)
__device__ __forceinline__ float shup1(float v) {
    return __int_as_float(__builtin_amdgcn_update_dpp(
        0, __float_as_int(v), 0x138, 0xF, 0xF, false));
}

// Lane-systolic DTW, R=4 rows/step, KC=4 cols/lane, 1-step lane stagger.
// Handoff: RTS=16 steps per tile -> 64 boundary rows per flag, which exactly
// fills all 64 lanes of vbuf. Boundary tile t+1 is PREFETCHED into vnext 4
// steps before it is consumed, so the acquire-load + cross-XCD bnd miss sit
// off the critical path in steady state. Stage stores are nontemporal (no L2
// dirtying -> the release-store's vmcnt-drain + buffer_wbl2 are cheap); bnd
// and MODE-0 out stores stay plain (they carry cross-wave data / rely on L2
// write-merging).
template <int MODE>
__global__ void __launch_bounds__(64) dtw_main(const float* __restrict__ x,
                                               const float* __restrict__ y,
                                               float* __restrict__ out,
                                               int* __restrict__ flags,
                                               float* __restrict__ bnd,
                                               float* __restrict__ stage) {
    const int g    = blockIdx.x;
    const int lane = threadIdx.x;
    const int j0   = g * WCH;
    const int c0   = j0 + lane * KC;

    float yv[KC], cur[KC];
#pragma unroll
    for (int q = 0; q < KC; ++q) {
        yv[q]  = y[c0 + q];
        cur[q] = FINF;                   // dtw[0][col] = INF
    }
    float pl = (c0 == 0) ? 0.0f : FINF;  // diag seed: dtw[0][0] = 0
    float rlast[R];
#pragma unroll
    for (int r = 0; r < R; ++r) rlast[r] = FINF;
    float vbuf = FINF, vnext = FINF;

    // x register window, double-buffered: x4[w*64+lane] = x[4*(w*64+lane)..+3]
    const float4* x4 = (const float4*)x;
    float4 xw  = x4[lane];
    float4 xwN = x4[64 + lane];
    float xcur[R];
#pragma unroll
    for (int r = 0; r < R; ++r) xcur[r] = x[r];

    float cnx[R][KC];                    // (x-y)^2 for the CURRENT step
#pragma unroll
    for (int r = 0; r < R; ++r)
#pragma unroll
        for (int q = 0; q < KC; ++q) {
            const float d = xcur[r] - yv[q];
            cnx[r][q] = d * d;
        }

    int off = (1 - R * lane) * MP1 + c0 + 1;   // direct-mode out offset

    // ---- prefetch tile 0 boundary (rows 0..63) before the loop ----
    if (g != 0) {
        while (__hip_atomic_load(&flags[(g - 1) * 16], __ATOMIC_ACQUIRE,
                                 __HIP_MEMORY_SCOPE_AGENT) < 1) {
            __builtin_amdgcn_s_sleep(1);
        }
        vnext = bnd ? bnd[(size_t)(g - 1) * NN + lane]
                    : out[(size_t)(1 + lane) * MP1 + j0];
    }

    for (int s = 0; s < STEPS; ++s) {
        // ---- consume the prefetched boundary tile ----
        if (g != 0 && s < NWS && (s & (RTS - 1)) == 0) vbuf = vnext;

        // ---- prefetch next tile's 64 boundary rows, 4 steps early ----
        if (g != 0 && (s & (RTS - 1)) == RTS - 4 && (s + 4) < NWS) {
            const int want = ((s + 4) >> 4) + 1;
            while (__hip_atomic_load(&flags[(g - 1) * 16], __ATOMIC_ACQUIRE,
                                     __HIP_MEMORY_SCOPE_AGENT) < want) {
                __builtin_amdgcn_s_sleep(1);
            }
            vnext = bnd ? bnd[(size_t)(g - 1) * NN + (size_t)R * (s + 4) + lane]
                        : out[(size_t)(R * (s + 4) + 1 + lane) * MP1 + j0];
        }

        // ---- carries: DPP wave_shr1 of last step's right edges ----
        float vin[R];
#pragma unroll
        for (int r = 0; r < R; ++r) {
            const float up = shup1(rlast[r]);
            const float vb = readlane_f(vbuf, ((s & (RTS - 1)) << 2) + r);
            const float l0 = (g == 0) ? FINF : vb;
            vin[r] = (lane == 0) ? l0 : up;
        }

        const bool active = (s >= lane) && (s - lane < NWS);
        if (active) {
#pragma unroll
            for (int r = 0; r < R; ++r) {
                float rl  = vin[r];
                float pm1 = (r == 0) ? pl : vin[r - 1];
                float nv[KC];
#pragma unroll
                for (int q = 0; q < KC; ++q) {
                    const float upv = cur[q];
                    rl     = cnx[r][q] + fminf(fminf(rl, upv), pm1);
                    pm1    = upv;
                    cur[q] = rl;
                    nv[q]  = rl;
                }
                rlast[r] = rl;
                if (MODE == 1) {
                    float* sb = stage + (((size_t)(g * STEPS + s)) << 10);
                    __builtin_nontemporal_store(
                        (f4v){nv[0], nv[1], nv[2], nv[3]},
                        (f4v*)(sb + (r << 8) + (lane << 2)));
                } else {
                    *(f4a*)(&out[off + r * MP1]) =
                        (f4a){nv[0], nv[1], nv[2], nv[3]};
                }
            }
            pl = vin[R - 1];
            if (bnd && lane == 63) {
                *(f4a*)&bnd[(size_t)g * NN + R * (s - 63)] =
                    (f4a){rlast[0], rlast[1], rlast[2], rlast[3]};
            }
        }
        off += R * MP1;

        // ---- x for next step (off the carry chain) ----
        const int sn = s + 1;
        if ((sn & 63) == 0) {
            xw = xwN;
            int nb = sn + 64 + lane;
            if (nb > NN / 4 - 1) nb = NN / 4 - 1;
            xwN = x4[nb];
        }
        const float* xwp = (const float*)&xw;
#pragma unroll
        for (int r = 0; r < R; ++r) {
            const float xs = shup1(xcur[r]);
            const float xj = readlane_f(xwp[r], sn & 63);
            xcur[r] = (lane == 0) ? xj : xs;
        }
#pragma unroll
        for (int r = 0; r < R; ++r)
#pragma unroll
            for (int q = 0; q < KC; ++q) {
                const float d = xcur[r] - yv[q];
                cnx[r][q] = d * d;
            }

        // ---- producer: publish every 64 completed boundary rows ----
        // RELEASE store carries the fence (vmcnt drain + wbl2) itself; the
        // previous explicit __threadfence() was a duplicate of it.
        if (g != GCH - 1 && s > 62 && ((s - 62) & (RTS - 1)) == 0) {
            if (lane == 0)
                __hip_atomic_store(&flags[g * 16], (s - 62) >> 4,
                                   __ATOMIC_RELEASE, __HIP_MEMORY_SCOPE_AGENT);
        }
    }
}

// Staged mode: read stage coalesced (nontemporal — no reuse), sqrt, scatter
// 16B chunks into out (plain stores: L2 merges neighboring partial lines).
__global__ void __launch_bounds__(64) scatter_pass(const float* __restrict__ stage,
                                                   float* __restrict__ out) {
    const int b = blockIdx.x;            // b = g*STEPS + s
    const int g = b / STEPS;
    const int s = b - g * STEPS;
    const int l = threadIdx.x;
    const int t = s - l;
    if (t < 0 || t >= NWS) return;
    const float* sb = stage + (((size_t)b) << 10) + (l << 2);
    float* ob = out + (size_t)(R * t + 1) * MP1 + g * WCH + l * KC + 1;
#pragma unroll
    for (int r = 0; r < R; ++r) {
        f4v v = __builtin_nontemporal_load((const f4v*)(sb + (r << 8)));
        f4a o = {__builtin_amdgcn_sqrtf(v.x), __builtin_amdgcn_sqrtf(v.y),
                 __builtin_amdgcn_sqrtf(v.z), __builtin_amdgcn_sqrtf(v.w)};
        *(f4a*)(ob + r * MP1) = o;
    }
}

// Direct mode: in-place sqrt over the whole table (incl. raw edges).
__global__ void sqrt_inplace(float* __restrict__ out, int n4, long long total) {
    const int i = blockIdx.x * blockDim.x + threadIdx.x;
    if (i < n4) {
        f4v v = ((f4v*)out)[i];
        v = (f4v){__builtin_amdgcn_sqrtf(v.x), __builtin_amdgcn_sqrtf(v.y),
                  __builtin_amdgcn_sqrtf(v.z), __builtin_amdgcn_sqrtf(v.w)};
        ((f4v*)out)[i] = v;
    } else if (i == n4) {
        for (long long j = (long long)n4 * 4; j < total; ++j)
            out[j] = __builtin_amdgcn_sqrtf(out[j]);
    }
}

// Row 0 / column 0 sentinels; `ev` is INF (direct mode, sqrt'd later) or
// sqrt(INF) (staged mode, final).
__global__ void dtw_edges(float* __restrict__ out, float ev) {
    const int idx = blockIdx.x * blockDim.x + threadIdx.x;
    if (idx <= NN) {
        out[idx] = (idx == 0) ? 0.0f : ev;          // row 0
        if (idx >= 1) out[(size_t)idx * MP1] = ev;  // column 0
    }
}

extern "C" void kernel_launch(void* const* d_in, const int* in_sizes, int n_in,
                              void* d_out, int out_size, void* d_ws, size_t ws_size,
                              hipStream_t stream) {
    (void)in_sizes; (void)n_in; (void)out_size;
    const float* x = (const float*)d_in[0];
    const float* y = (const float*)d_in[1];
    float* out     = (float*)d_out;
    int* flags     = (int*)d_ws;

    const size_t bnd_off      = 4096;
    const size_t bnd_bytes    = (size_t)GCH * NN * sizeof(float);     // 576 KB
    const size_t stage_off    = bnd_off + bnd_bytes;                  // 593920
    const size_t stage_bytes  = (size_t)GCH * STEPS * 4096;           // ~150 MB
    const size_t stage_needed = stage_off + stage_bytes;

    float* bnd   = (ws_size >= stage_off) ? (float*)((char*)d_ws + bnd_off) : nullptr;
    float* stage = (ws_size >= stage_needed) ? (float*)((char*)d_ws + stage_off) : nullptr;

    hipMemsetAsync(flags, 0, GCH * 16 * sizeof(int), stream);

    const long long total = (long long)MP1 * MP1;   // 37,761,025
    const int n4 = (int)(total / 4);

    if (stage) {
        dtw_edges<<<(MP1 + 255) / 256, 256, 0, stream>>>(out, sqrtf(FINF));
        dtw_main<1><<<GCH, 64, 0, stream>>>(x, y, out, flags, bnd, stage);
        scatter_pass<<<GCH * STEPS, 64, 0, stream>>>(stage, out);
    } else {
        dtw_edges<<<(MP1 + 255) / 256, 256, 0, stream>>>(out, FINF);
        dtw_main<0><<<GCH, 64, 0, stream>>>(x, y, out, flags, bnd, nullptr);
        sqrt_inplace<<<(n4 + 256) / 256, 256, 0, stream>>>(out, n4, total);
    }
}

// Round 2
// 1763.120 us; speedup vs baseline: 1.1828x; 1.0632x over previous
//
#include <hip/hip_runtime.h>
#include <math.h>

#define NN    6144
#define MP1   6145
#define R     4                  // rows per lane per step
#define KC    4                  // columns per lane
#define WCH   (KC * 64)          // 256 columns per wave
#define GCH   (NN / WCH)         // 24 strips / waves in the systolic chain
#define RTS   16                 // steps per handoff tile (= 64 rows / flag)
#define NWS   (NN / R)           // 1536 working steps per wave
#define STEPS (NWS + 63)         // + lane-stagger fill = 1599
#define FINF  99999.0f

// ---- phase-2 tiling ----
#define BR     384               // rows per band
#define NBI    (NN / BR)         // 16 bands
#define TS2    (BR / R)          // 96 work steps per tile
#define STEPS2 (TS2 + 63)        // 159 steps incl. lane stagger

typedef float f4a __attribute__((ext_vector_type(4), aligned(4)));   // unaligned-ok store
typedef float f4v __attribute__((ext_vector_type(4), aligned(16)));  // aligned vec

__device__ __forceinline__ float readlane_f(float v, int l) {
    return __int_as_float(__builtin_amdgcn_readlane(__float_as_int(v), l));
}
// lane i <- lane i-1, via DPP wave_shr:1 (VALU-speed)
__device__ __forceinline__ float shup1(float v) {
    return __int_as_float(__builtin_amdgcn_update_dpp(
        0, __float_as_int(v), 0x138, 0xF, 0xF, false));
}

// ============================ PHASE 1 ============================
// Lane-systolic DTW over the full table, storing ONLY boundaries:
//   bnd[g][i]  = table(i+1, 256*(g+1))   (strip right edges, per step, lane 63)
//   rowb[k][j] = table(384*k, j), k=1..15 (band top rows, one store / 96 steps)
// No bulk table stores -> the per-wave store-drain stall (theory: ~900 cy/step)
// leaves the critical path. Handoff: RTS=16 (64 rows/flag), tile prefetched 4
// steps early into vnext so the acquire + cross-XCD bnd miss are off-path.
__global__ void __launch_bounds__(64) dtw_bnd(const float* __restrict__ x,
                                              const float* __restrict__ y,
                                              int* __restrict__ flags,
                                              float* __restrict__ bnd,
                                              float* __restrict__ rowb) {
    const int g    = blockIdx.x;
    const int lane = threadIdx.x;
    const int j0   = g * WCH;
    const int c0   = j0 + lane * KC;

    float yv[KC], cur[KC];
#pragma unroll
    for (int q = 0; q < KC; ++q) {
        yv[q]  = y[c0 + q];
        cur[q] = FINF;                   // dtw[0][col] = INF
    }
    float pl = (c0 == 0) ? 0.0f : FINF;  // diag seed: dtw[0][0] = 0
    float rlast[R];
#pragma unroll
    for (int r = 0; r < R; ++r) rlast[r] = FINF;
    float vbuf = FINF, vnext = FINF;

    // x register window, double-buffered: x4[w*64+lane] = x[4*(w*64+lane)..+3]
    const float4* x4 = (const float4*)x;
    float4 xw  = x4[lane];
    float4 xwN = x4[64 + lane];
    float xcur[R];
#pragma unroll
    for (int r = 0; r < R; ++r) xcur[r] = x[r];

    float cnx[R][KC];                    // (x-y)^2 for the CURRENT step
#pragma unroll
    for (int r = 0; r < R; ++r)
#pragma unroll
        for (int q = 0; q < KC; ++q) {
            const float d = xcur[r] - yv[q];
            cnx[r][q] = d * d;
        }

    // ---- prefetch tile 0 boundary (rows 0..63) before the loop ----
    if (g != 0) {
        while (__hip_atomic_load(&flags[(g - 1) * 16], __ATOMIC_ACQUIRE,
                                 __HIP_MEMORY_SCOPE_AGENT) < 1) {
            __builtin_amdgcn_s_sleep(1);
        }
        vnext = bnd[(size_t)(g - 1) * NN + lane];
    }

    for (int s = 0; s < STEPS; ++s) {
        // ---- consume the prefetched boundary tile ----
        if (g != 0 && s < NWS && (s & (RTS - 1)) == 0) vbuf = vnext;

        // ---- prefetch next tile's 64 boundary rows, 4 steps early ----
        if (g != 0 && (s & (RTS - 1)) == RTS - 4 && (s + 4) < NWS) {
            const int want = ((s + 4) >> 4) + 1;
            while (__hip_atomic_load(&flags[(g - 1) * 16], __ATOMIC_ACQUIRE,
                                     __HIP_MEMORY_SCOPE_AGENT) < want) {
                __builtin_amdgcn_s_sleep(1);
            }
            vnext = bnd[(size_t)(g - 1) * NN + (size_t)R * (s + 4) + lane];
        }

        // ---- carries: DPP wave_shr1 of last step's right edges ----
        float vin[R];
#pragma unroll
        for (int r = 0; r < R; ++r) {
            const float up = shup1(rlast[r]);
            const float vb = readlane_f(vbuf, ((s & (RTS - 1)) << 2) + r);
            const float l0 = (g == 0) ? FINF : vb;
            vin[r] = (lane == 0) ? l0 : up;
        }

        const bool active = (s >= lane) && (s - lane < NWS);
        if (active) {
#pragma unroll
            for (int r = 0; r < R; ++r) {
                float rl  = vin[r];
                float pm1 = (r == 0) ? pl : vin[r - 1];
                float nv[KC];
#pragma unroll
                for (int q = 0; q < KC; ++q) {
                    const float upv = cur[q];
                    rl     = cnx[r][q] + fminf(fminf(rl, upv), pm1);
                    pm1    = upv;
                    cur[q] = rl;
                    nv[q]  = rl;
                }
                rlast[r] = rl;
                if (r == R - 1) {
                    // band top rows: table row 384k is r=3 of work step t=96k-1
                    const int tp1 = s - lane + 1;
                    const int k   = tp1 / 96;
                    if (k * 96 == tp1 && k >= 1 && k <= NBI - 1) {
                        *(f4a*)&rowb[(size_t)k * MP1 + c0 + 1] =
                            (f4a){nv[0], nv[1], nv[2], nv[3]};
                    }
                }
            }
            pl = vin[R - 1];
            if (lane == 63) {
                *(f4a*)&bnd[(size_t)g * NN + R * (s - 63)] =
                    (f4a){rlast[0], rlast[1], rlast[2], rlast[3]};
            }
        }

        // ---- x for next step (off the carry chain) ----
        const int sn = s + 1;
        if ((sn & 63) == 0) {
            xw = xwN;
            int nb = sn + 64 + lane;
            if (nb > NN / 4 - 1) nb = NN / 4 - 1;
            xwN = x4[nb];
        }
        const float* xwp = (const float*)&xw;
#pragma unroll
        for (int r = 0; r < R; ++r) {
            const float xs = shup1(xcur[r]);
            const float xj = readlane_f(xwp[r], sn & 63);
            xcur[r] = (lane == 0) ? xj : xs;
        }
#pragma unroll
        for (int r = 0; r < R; ++r)
#pragma unroll
            for (int q = 0; q < KC; ++q) {
                const float d = xcur[r] - yv[q];
                cnx[r][q] = d * d;
            }

        // ---- producer: publish every 64 completed boundary rows ----
        if (g != GCH - 1 && s > 62 && ((s - 62) & (RTS - 1)) == 0) {
            if (lane == 0)
                __hip_atomic_store(&flags[g * 16], (s - 62) >> 4,
                                   __ATOMIC_RELEASE, __HIP_MEMORY_SCOPE_AGENT);
        }
    }
}

// ============================ PHASE 2 ============================
// 384 independent 384-row x 256-col tiles, seeded from bnd (left edge) and
// rowb (top edge). Identical evaluation order as phase 1 -> bit-identical
// values. sqrt fused into the final coalesced stores straight into out.
__global__ void __launch_bounds__(64) dtw_tile(const float* __restrict__ x,
                                               const float* __restrict__ y,
                                               const float* __restrict__ bnd,
                                               const float* __restrict__ rowb,
                                               float* __restrict__ out) {
    const int bj   = blockIdx.x;         // strip  (column block, 0..23)
    const int bi   = blockIdx.y;         // band   (row block,    0..15)
    const int lane = threadIdx.x;

    __shared__ float left_s[BR];         // left boundary col, rows +1..+384
    __shared__ float top_s[WCH + 1];     // top boundary row, local cols 0..256
    __shared__ float xb_s[BR];           // x for this band

    for (int k = 0; k < BR / 64; ++k) {
        const int i = 64 * k + lane;     // 0..383
        left_s[i] = (bj == 0) ? FINF
                              : bnd[(size_t)(bj - 1) * NN + BR * bi + i];
        xb_s[i] = x[BR * bi + i];
    }
    for (int c = lane; c < WCH + 1; c += 64) {
        float tv;
        if (bi == 0)      tv = (bj == 0 && c == 0) ? 0.0f : FINF;
        else if (c == 0 && bj == 0) tv = FINF;   // table col 0 sentinel
        else              tv = rowb[(size_t)bi * MP1 + WCH * bj + c];
        top_s[c] = tv;
    }
    __syncthreads();

    const int c0 = WCH * bj + KC * lane; // first table col - 1 for this lane
    float yv[KC], cur[KC];
#pragma unroll
    for (int q = 0; q < KC; ++q) {
        yv[q]  = y[c0 + q];
        cur[q] = top_s[KC * lane + q + 1];
    }
    float pl = top_s[KC * lane];         // diag seed for the lane's first row
    float rlast[R];
#pragma unroll
    for (int r = 0; r < R; ++r) rlast[r] = FINF;

    float xcur[R];
#pragma unroll
    for (int r = 0; r < R; ++r) xcur[r] = xb_s[r];
    float cnx[R][KC];
#pragma unroll
    for (int r = 0; r < R; ++r)
#pragma unroll
        for (int q = 0; q < KC; ++q) {
            const float d = xcur[r] - yv[q];
            cnx[r][q] = d * d;
        }

    int off = (BR * bi + 1 - R * lane) * MP1 + c0 + 1;  // out offset (row of t=0)

    for (int s = 0; s < STEPS2; ++s) {
        float vin[R];
#pragma unroll
        for (int r = 0; r < R; ++r) {
            const float up = shup1(rlast[r]);
            const int  li  = R * s + r;               // lane0's left idx (uniform)
            const float l0 = left_s[li < BR ? li : BR - 1];
            vin[r] = (lane == 0) ? l0 : up;
        }

        const int  t      = s - lane;
        const bool active = (t >= 0) && (t < TS2);
        if (active) {
#pragma unroll
            for (int r = 0; r < R; ++r) {
                float rl  = vin[r];
                float pm1 = (r == 0) ? pl : vin[r - 1];
                float nv[KC];
#pragma unroll
                for (int q = 0; q < KC; ++q) {
                    const float upv = cur[q];
                    rl     = cnx[r][q] + fminf(fminf(rl, upv), pm1);
                    pm1    = upv;
                    cur[q] = rl;
                    nv[q]  = rl;
                }
                rlast[r] = rl;
                *(f4a*)(&out[off + r * MP1]) =
                    (f4a){__builtin_amdgcn_sqrtf(nv[0]),
                          __builtin_amdgcn_sqrtf(nv[1]),
                          __builtin_amdgcn_sqrtf(nv[2]),
                          __builtin_amdgcn_sqrtf(nv[3])};
            }
            pl = vin[R - 1];
        }
        off += R * MP1;

        // ---- x for next step ----
        const int sn = s + 1;
#pragma unroll
        for (int r = 0; r < R; ++r) {
            const float xs = shup1(xcur[r]);
            const int  xi  = R * sn + r;
            const float xj = xb_s[xi < BR ? xi : BR - 1];
            xcur[r] = (lane == 0) ? xj : xs;
        }
#pragma unroll
        for (int r = 0; r < R; ++r)
#pragma unroll
            for (int q = 0; q < KC; ++q) {
                const float d = xcur[r] - yv[q];
                cnx[r][q] = d * d;
            }
    }
}

// Row 0 / column 0 sentinels (final, sqrt'd).
__global__ void dtw_edges(float* __restrict__ out, float ev) {
    const int idx = blockIdx.x * blockDim.x + threadIdx.x;
    if (idx <= NN) {
        out[idx] = (idx == 0) ? 0.0f : ev;          // row 0
        if (idx >= 1) out[(size_t)idx * MP1] = ev;  // column 0
    }
}

extern "C" void kernel_launch(void* const* d_in, const int* in_sizes, int n_in,
                              void* d_out, int out_size, void* d_ws, size_t ws_size,
                              hipStream_t stream) {
    (void)in_sizes; (void)n_in; (void)out_size; (void)ws_size;
    const float* x = (const float*)d_in[0];
    const float* y = (const float*)d_in[1];
    float* out     = (float*)d_out;
    int* flags     = (int*)d_ws;

    const size_t bnd_off  = 4096;
    const size_t bnd_sz   = (size_t)GCH * NN * sizeof(float);    // 576 KB
    const size_t rowb_off = bnd_off + bnd_sz;                    // 593920
    float* bnd  = (float*)((char*)d_ws + bnd_off);
    float* rowb = (float*)((char*)d_ws + rowb_off);              // 16*6145*4 B

    hipMemsetAsync(flags, 0, GCH * 16 * sizeof(int), stream);

    dtw_edges<<<(MP1 + 255) / 256, 256, 0, stream>>>(out, sqrtf(FINF));
    dtw_bnd<<<GCH, 64, 0, stream>>>(x, y, flags, bnd, rowb);
    dtw_tile<<<dim3(GCH, NBI), 64, 0, stream>>>(x, y, bnd, rowb, out);
}

// Round 3
// 1571.373 us; speedup vs baseline: 1.3271x; 1.1220x over previous
//
#include <hip/hip_runtime.h>
#include <math.h>

#define NN    6144
#define MP1   6145
#define FINF  99999.0f

// ---- phase 1: boundary-only systolic chain (widened R=KC=8) ----
#define R1     8                 // rows per lane per step
#define KC1    8                 // columns per lane
#define WCH1   (KC1 * 64)        // 512 cols per wave
#define GCH1   (NN / WCH1)       // 12 strips
#define RTS1   8                 // steps per flag (= 64 boundary rows)
#define NWS1   (NN / R1)         // 768 work steps
#define STEPS1 (NWS1 + 63)       // 831 incl. lane stagger

// ---- phase 2: independent tiles (KC=8 to match 512-col strips) ----
#define R2     4
#define KC2    8
#define WCH2   (KC2 * 64)        // 512 cols per tile
#define BR     384               // rows per band
#define NBI    (NN / BR)         // 16 bands
#define TS2    (BR / R2)         // 96 work steps
#define STEPS2 (TS2 + 63)        // 159

typedef float f4a __attribute__((ext_vector_type(4), aligned(4)));   // unaligned-ok store
typedef float f4v __attribute__((ext_vector_type(4), aligned(16)));  // aligned vec

__device__ __forceinline__ float readlane_f(float v, int l) {
    return __int_as_float(__builtin_amdgcn_readlane(__float_as_int(v), l));
}
// lane i <- lane i-1, via DPP wave_shr:1 (VALU-speed)
__device__ __forceinline__ float shup1(float v) {
    return __int_as_float(__builtin_amdgcn_update_dpp(
        0, __float_as_int(v), 0x138, 0xF, 0xF, false));
}

// ============================ PHASE 1 ============================
// Lane-systolic DTW over the full table, 8 rows x 8 cols per lane per step.
// Stores ONLY boundaries:
//   bnd[g][i]  = table(i+1, 512*(g+1))   (strip right edge, lane 63)
//   rowb[k][j] = table(384*k, j), k=1..15 (band top rows)
// Path = 831 + 11*~76 steps (vs 3485 at R=KC=4): amortizes the measured
// ~860 cy/step fixed overhead over 4x the cells. Publish at TOP of step with
// 1-step slack so release's vmcnt(0) waits on already-retired stores.
__global__ void __launch_bounds__(64) dtw_bnd(const float* __restrict__ x,
                                              const float* __restrict__ y,
                                              int* __restrict__ flags,
                                              float* __restrict__ bnd,
                                              float* __restrict__ rowb) {
    const int g    = blockIdx.x;
    const int lane = threadIdx.x;
    const int c0   = g * WCH1 + lane * KC1;

    float yv[KC1], cur[KC1];
#pragma unroll
    for (int q = 0; q < KC1; ++q) {
        yv[q]  = y[c0 + q];
        cur[q] = FINF;                   // dtw[0][col] = INF
    }
    float pl = (c0 == 0) ? 0.0f : FINF;  // diag seed: dtw[0][0] = 0
    float rlast[R1];
#pragma unroll
    for (int r = 0; r < R1; ++r) rlast[r] = FINF;
    float vbuf = FINF, vnext = FINF;

    // x register window: per 64-step window w, lane m holds x[8*(64w+m) .. +7]
    // as two float4s; double-buffered.
    const float4* x4 = (const float4*)x;
    float4 xwA  = x4[2 * lane];
    float4 xwB  = x4[2 * lane + 1];
    float4 xwAN = x4[2 * (64 + lane)];
    float4 xwBN = x4[2 * (64 + lane) + 1];
    float xcur[R1];
#pragma unroll
    for (int r = 0; r < R1; ++r) xcur[r] = x[r];

    float cnx[R1][KC1];                  // (x-y)^2 for the CURRENT step
#pragma unroll
    for (int r = 0; r < R1; ++r)
#pragma unroll
        for (int q = 0; q < KC1; ++q) {
            const float d = xcur[r] - yv[q];
            cnx[r][q] = d * d;
        }

    // ---- prefetch tile 0 boundary (rows 0..63) before the loop ----
    if (g != 0) {
        while (__hip_atomic_load(&flags[(g - 1) * 16], __ATOMIC_ACQUIRE,
                                 __HIP_MEMORY_SCOPE_AGENT) < 1) {
            __builtin_amdgcn_s_sleep(1);
        }
        vnext = bnd[(size_t)(g - 1) * NN + lane];
    }

    for (int s = 0; s < STEPS1; ++s) {
        // ---- producer publish (top of step, >=1 full step of store slack) ----
        if (g != GCH1 - 1 && s > 64 && ((s - 64) & (RTS1 - 1)) == 0) {
            if (lane == 0)
                __hip_atomic_store(&flags[g * 16], (s - 64) >> 3,
                                   __ATOMIC_RELEASE, __HIP_MEMORY_SCOPE_AGENT);
        }

        // ---- consume the prefetched boundary window ----
        if (g != 0 && s < NWS1 && (s & (RTS1 - 1)) == 0) vbuf = vnext;

        // ---- prefetch next window's 64 boundary rows, 4 steps early ----
        if (g != 0 && (s & (RTS1 - 1)) == RTS1 - 4 && (s + 4) < NWS1) {
            const int want = ((s + 4) >> 3) + 1;
            while (__hip_atomic_load(&flags[(g - 1) * 16], __ATOMIC_ACQUIRE,
                                     __HIP_MEMORY_SCOPE_AGENT) < want) {
                __builtin_amdgcn_s_sleep(1);
            }
            vnext = bnd[(size_t)(g - 1) * NN + (size_t)R1 * (s + 4) + lane];
        }

        // ---- carries: DPP wave_shr1 of last step's right edges ----
        float vin[R1];
#pragma unroll
        for (int r = 0; r < R1; ++r) {
            const float up = shup1(rlast[r]);
            const float vb = readlane_f(vbuf, ((s & (RTS1 - 1)) << 3) + r);
            const float l0 = (g == 0) ? FINF : vb;
            vin[r] = (lane == 0) ? l0 : up;
        }

        const int  t      = s - lane;
        const bool active = (t >= 0) && (t < NWS1);
        if (active) {
#pragma unroll
            for (int r = 0; r < R1; ++r) {
                float rl  = vin[r];
                float pm1 = (r == 0) ? pl : vin[r - 1];
                float nv[KC1];
#pragma unroll
                for (int q = 0; q < KC1; ++q) {
                    const float upv = cur[q];
                    rl     = cnx[r][q] + fminf(fminf(rl, upv), pm1);
                    pm1    = upv;
                    cur[q] = rl;
                    nv[q]  = rl;
                }
                rlast[r] = rl;
                if (r == R1 - 1) {
                    // band top rows: row 384k is r=7 of work step t=48k-1
                    const int tp1 = t + 1;
                    const int k   = tp1 / 48;
                    if (k * 48 == tp1 && k >= 1 && k <= NBI - 1) {
                        *(f4a*)&rowb[(size_t)k * MP1 + c0 + 1] =
                            (f4a){nv[0], nv[1], nv[2], nv[3]};
                        *(f4a*)&rowb[(size_t)k * MP1 + c0 + 5] =
                            (f4a){nv[4], nv[5], nv[6], nv[7]};
                    }
                }
            }
            pl = vin[R1 - 1];
            if (lane == 63) {
                *(f4v*)&bnd[(size_t)g * NN + (size_t)R1 * t] =
                    (f4v){rlast[0], rlast[1], rlast[2], rlast[3]};
                *(f4v*)&bnd[(size_t)g * NN + (size_t)R1 * t + 4] =
                    (f4v){rlast[4], rlast[5], rlast[6], rlast[7]};
            }
        }

        // ---- x for next step (off the carry chain) ----
        const int sn = s + 1;
        if ((sn & 63) == 0) {
            xwA = xwAN;
            xwB = xwBN;
            int nb = sn + 64 + lane;                 // float8-unit index
            if (nb > NN / 8 - 1) nb = NN / 8 - 1;
            xwAN = x4[2 * nb];
            xwBN = x4[2 * nb + 1];
        }
        const float* xap = (const float*)&xwA;
        const float* xbp = (const float*)&xwB;
#pragma unroll
        for (int r = 0; r < 4; ++r) {
            const float xs = shup1(xcur[r]);
            const float xj = readlane_f(xap[r], sn & 63);
            xcur[r] = (lane == 0) ? xj : xs;
        }
#pragma unroll
        for (int r = 4; r < 8; ++r) {
            const float xs = shup1(xcur[r]);
            const float xj = readlane_f(xbp[r - 4], sn & 63);
            xcur[r] = (lane == 0) ? xj : xs;
        }
#pragma unroll
        for (int r = 0; r < R1; ++r)
#pragma unroll
            for (int q = 0; q < KC1; ++q) {
                const float d = xcur[r] - yv[q];
                cnx[r][q] = d * d;
            }
    }

    // final window flag (k = 96) — its producing step is the last loop step
    if (g != GCH1 - 1 && lane == 0) {
        __hip_atomic_store(&flags[g * 16], NWS1 >> 3,
                           __ATOMIC_RELEASE, __HIP_MEMORY_SCOPE_AGENT);
    }
}

// ============================ PHASE 2 ============================
// 192 independent 384-row x 512-col tiles, seeded from bnd (left edge) and
// rowb (top edge). Per-cell math identical -> bit-identical values. sqrt
// fused into coalesced stores straight into out.
__global__ void __launch_bounds__(64) dtw_tile(const float* __restrict__ x,
                                               const float* __restrict__ y,
                                               const float* __restrict__ bnd,
                                               const float* __restrict__ rowb,
                                               float* __restrict__ out) {
    const int bj   = blockIdx.x;         // strip  (column block, 0..11)
    const int bi   = blockIdx.y;         // band   (row block,    0..15)
    const int lane = threadIdx.x;

    __shared__ float left_s[BR];         // left boundary col, rows +1..+384
    __shared__ float top_s[WCH2 + 1];    // top boundary row, local cols 0..512
    __shared__ float xb_s[BR];           // x for this band

#pragma unroll
    for (int k = 0; k < BR / 64; ++k) {
        const int i = 64 * k + lane;     // 0..383
        left_s[i] = (bj == 0) ? FINF
                              : bnd[(size_t)(bj - 1) * NN + BR * bi + i];
        xb_s[i] = x[BR * bi + i];
    }
    for (int c = lane; c < WCH2 + 1; c += 64) {
        float tv;
        if (bi == 0)                tv = (bj == 0 && c == 0) ? 0.0f : FINF;
        else if (c == 0 && bj == 0) tv = FINF;   // table col 0 sentinel
        else                        tv = rowb[(size_t)bi * MP1 + WCH2 * bj + c];
        top_s[c] = tv;
    }
    __syncthreads();

    const int c0 = WCH2 * bj + KC2 * lane;
    float yv[KC2], cur[KC2];
#pragma unroll
    for (int q = 0; q < KC2; ++q) {
        yv[q]  = y[c0 + q];
        cur[q] = top_s[KC2 * lane + q + 1];
    }
    float pl = top_s[KC2 * lane];        // diag seed for the lane's first row
    float rlast[R2];
#pragma unroll
    for (int r = 0; r < R2; ++r) rlast[r] = FINF;

    float xcur[R2];
#pragma unroll
    for (int r = 0; r < R2; ++r) xcur[r] = xb_s[r];
    float cnx[R2][KC2];
#pragma unroll
    for (int r = 0; r < R2; ++r)
#pragma unroll
        for (int q = 0; q < KC2; ++q) {
            const float d = xcur[r] - yv[q];
            cnx[r][q] = d * d;
        }

    int off = (BR * bi + 1 - R2 * lane) * MP1 + c0 + 1;  // out offset (t=0 row)

    for (int s = 0; s < STEPS2; ++s) {
        float vin[R2];
#pragma unroll
        for (int r = 0; r < R2; ++r) {
            const float up = shup1(rlast[r]);
            const int  li  = R2 * s + r;             // lane0's left idx (uniform)
            const float l0 = left_s[li < BR ? li : BR - 1];
            vin[r] = (lane == 0) ? l0 : up;
        }

        const int  t      = s - lane;
        const bool active = (t >= 0) && (t < TS2);
        if (active) {
#pragma unroll
            for (int r = 0; r < R2; ++r) {
                float rl  = vin[r];
                float pm1 = (r == 0) ? pl : vin[r - 1];
                float nv[KC2];
#pragma unroll
                for (int q = 0; q < KC2; ++q) {
                    const float upv = cur[q];
                    rl     = cnx[r][q] + fminf(fminf(rl, upv), pm1);
                    pm1    = upv;
                    cur[q] = rl;
                    nv[q]  = rl;
                }
                rlast[r] = rl;
                *(f4a*)(&out[off + r * MP1]) =
                    (f4a){__builtin_amdgcn_sqrtf(nv[0]),
                          __builtin_amdgcn_sqrtf(nv[1]),
                          __builtin_amdgcn_sqrtf(nv[2]),
                          __builtin_amdgcn_sqrtf(nv[3])};
                *(f4a*)(&out[off + r * MP1 + 4]) =
                    (f4a){__builtin_amdgcn_sqrtf(nv[4]),
                          __builtin_amdgcn_sqrtf(nv[5]),
                          __builtin_amdgcn_sqrtf(nv[6]),
                          __builtin_amdgcn_sqrtf(nv[7])};
            }
            pl = vin[R2 - 1];
        }
        off += R2 * MP1;

        // ---- x for next step ----
        const int sn = s + 1;
#pragma unroll
        for (int r = 0; r < R2; ++r) {
            const float xs = shup1(xcur[r]);
            const int  xi  = R2 * sn + r;
            const float xj = xb_s[xi < BR ? xi : BR - 1];
            xcur[r] = (lane == 0) ? xj : xs;
        }
#pragma unroll
        for (int r = 0; r < R2; ++r)
#pragma unroll
            for (int q = 0; q < KC2; ++q) {
                const float d = xcur[r] - yv[q];
                cnx[r][q] = d * d;
            }
    }
}

// Row 0 / column 0 sentinels (final, sqrt'd).
__global__ void dtw_edges(float* __restrict__ out, float ev) {
    const int idx = blockIdx.x * blockDim.x + threadIdx.x;
    if (idx <= NN) {
        out[idx] = (idx == 0) ? 0.0f : ev;          // row 0
        if (idx >= 1) out[(size_t)idx * MP1] = ev;  // column 0
    }
}

extern "C" void kernel_launch(void* const* d_in, const int* in_sizes, int n_in,
                              void* d_out, int out_size, void* d_ws, size_t ws_size,
                              hipStream_t stream) {
    (void)in_sizes; (void)n_in; (void)out_size; (void)ws_size;
    const float* x = (const float*)d_in[0];
    const float* y = (const float*)d_in[1];
    float* out     = (float*)d_out;
    int* flags     = (int*)d_ws;

    const size_t bnd_off  = 4096;
    const size_t bnd_sz   = (size_t)GCH1 * NN * sizeof(float);   // 288 KB
    const size_t rowb_off = bnd_off + bnd_sz;
    float* bnd  = (float*)((char*)d_ws + bnd_off);
    float* rowb = (float*)((char*)d_ws + rowb_off);              // 16*6145*4 B

    hipMemsetAsync(flags, 0, GCH1 * 16 * sizeof(int), stream);

    dtw_edges<<<(MP1 + 255) / 256, 256, 0, stream>>>(out, sqrtf(FINF));
    dtw_bnd<<<GCH1, 64, 0, stream>>>(x, y, flags, bnd, rowb);
    dtw_tile<<<dim3(GCH1, NBI), 64, 0, stream>>>(x, y, bnd, rowb, out);
}